// Round 1
// baseline (4718.163 us; speedup 1.0000x reference)
//
#include <hip/hip_runtime.h>
#include <cmath>

#define TILE 16

__device__ __forceinline__ float lrelu_f(float v) { return v >= 0.f ? v : 0.1f * v; }

// ---------------------------------------------------------------------------
// Build q_in = concat([warp(frame0, fb0), frame1, warp(frame2, ff1), ff1, fb0])
// q_in: (b, 100, H, W)
// ---------------------------------------------------------------------------
__global__ __launch_bounds__(256) void build_qin_kernel(
    const float* __restrict__ frame, const float* __restrict__ ff,
    const float* __restrict__ fb, float* __restrict__ qin, int H, int W)
{
    const int HW = H * W;
    int q = blockIdx.x * 256 + threadIdx.x;
    if (q >= HW) return;
    int b = blockIdx.y;
    int x = q % W, y = q / W;
    const long fbase = (long)b * 96 * HW;
    const long qbase = (long)b * 100 * HW;

    float fb0x = fb[((long)(b * 2 + 0) * 2 + 0) * HW + q];
    float fb0y = fb[((long)(b * 2 + 0) * 2 + 1) * HW + q];
    float ff1x = ff[((long)(b * 2 + 1) * 2 + 0) * HW + q];
    float ff1y = ff[((long)(b * 2 + 1) * 2 + 1) * HW + q];

    // warp01 = bilinear(frame[b,0], x+fb0x, y+fb0y), clamp (no zero pad)
    {
        float gx = (float)x + fb0x, gy = (float)y + fb0y;
        float x0f = floorf(gx), y0f = floorf(gy);
        float wx = gx - x0f, wy = gy - y0f;
        int x0 = min(max((int)x0f, 0), W - 1);
        int x1 = min(max((int)x0f + 1, 0), W - 1);
        int y0 = min(max((int)y0f, 0), H - 1);
        int y1 = min(max((int)y0f + 1, 0), H - 1);
        float w00 = (1.f - wx) * (1.f - wy), w10 = wx * (1.f - wy);
        float w01 = (1.f - wx) * wy, w11 = wx * wy;
        const float* img = frame + fbase;  // t = 0
        #pragma unroll 4
        for (int ch = 0; ch < 32; ++ch) {
            const float* p = img + (long)ch * HW;
            float v = p[y0 * W + x0] * w00 + p[y0 * W + x1] * w10 +
                      p[y1 * W + x0] * w01 + p[y1 * W + x1] * w11;
            qin[qbase + (long)ch * HW + q] = v;
        }
    }
    // frame[:,1]
    #pragma unroll 4
    for (int ch = 0; ch < 32; ++ch)
        qin[qbase + (long)(32 + ch) * HW + q] = frame[fbase + (long)(32 + ch) * HW + q];
    // warp21 = bilinear(frame[b,2], x+ff1x, y+ff1y)
    {
        float gx = (float)x + ff1x, gy = (float)y + ff1y;
        float x0f = floorf(gx), y0f = floorf(gy);
        float wx = gx - x0f, wy = gy - y0f;
        int x0 = min(max((int)x0f, 0), W - 1);
        int x1 = min(max((int)x0f + 1, 0), W - 1);
        int y0 = min(max((int)y0f, 0), H - 1);
        int y1 = min(max((int)y0f + 1, 0), H - 1);
        float w00 = (1.f - wx) * (1.f - wy), w10 = wx * (1.f - wy);
        float w01 = (1.f - wx) * wy, w11 = wx * wy;
        const float* img = frame + fbase + (long)64 * HW;  // t = 2
        #pragma unroll 4
        for (int ch = 0; ch < 32; ++ch) {
            const float* p = img + (long)ch * HW;
            float v = p[y0 * W + x0] * w00 + p[y0 * W + x1] * w10 +
                      p[y1 * W + x0] * w01 + p[y1 * W + x1] * w11;
            qin[qbase + (long)(64 + ch) * HW + q] = v;
        }
    }
    qin[qbase + 96L * HW + q] = ff1x;
    qin[qbase + 97L * HW + q] = ff1y;
    qin[qbase + 98L * HW + q] = fb0x;
    qin[qbase + 99L * HW + q] = fb0y;
}

// ---------------------------------------------------------------------------
// Generic direct 3x3 conv (cross-correlation, zero padding = DIL, dilation = DIL)
// One block = 16x16 output tile of one image; each thread accumulates all COUT.
// TWO_IN: channels [0, CIN/2) from in0, [CIN/2, CIN) from in1.
// ---------------------------------------------------------------------------
template <int CIN, int COUT, int DIL, bool LRELU, bool RESID, bool TWO_IN>
__global__ __launch_bounds__(256) void conv3x3_kernel(
    const float* __restrict__ in0, long in0_stride,
    const float* __restrict__ in1, long in1_stride,
    const float* __restrict__ wgt, const float* __restrict__ bias,
    const float* __restrict__ resid, long resid_stride,
    float* __restrict__ out, long out_stride,
    int H, int W, int tilesX)
{
    constexpr int S = TILE + 2 * DIL;
    __shared__ float smem[S * S];
    const int n = blockIdx.y;
    const int tx = blockIdx.x % tilesX, ty = blockIdx.x / tilesX;
    const int lx = threadIdx.x % TILE, ly = threadIdx.x / TILE;
    const int ox = tx * TILE + lx, oy = ty * TILE + ly;

    float acc[COUT];
    #pragma unroll
    for (int co = 0; co < COUT; ++co) acc[co] = bias[co];

    const float* inbase0 = in0 + (long)n * in0_stride;
    const float* inbase1 = TWO_IN ? (in1 + (long)n * in1_stride) : nullptr;

    for (int ci = 0; ci < CIN; ++ci) {
        const float* src;
        if (TWO_IN && ci >= CIN / 2)
            src = inbase1 + (long)(ci - CIN / 2) * H * W;
        else
            src = inbase0 + (long)ci * H * W;
        // stage (TILE+2*DIL)^2 tile with zero padding
        for (int i = threadIdx.x; i < S * S; i += 256) {
            int sy = i / S, sx = i % S;
            int gy = ty * TILE - DIL + sy, gx = tx * TILE - DIL + sx;
            float v = 0.f;
            if (gy >= 0 && gy < H && gx >= 0 && gx < W) v = src[(long)gy * W + gx];
            smem[i] = v;
        }
        __syncthreads();
        float vv[9];
        #pragma unroll
        for (int dy = 0; dy < 3; ++dy)
            #pragma unroll
            for (int dx = 0; dx < 3; ++dx)
                vv[dy * 3 + dx] = smem[(ly + dy * DIL) * S + (lx + dx * DIL)];
        const float* wp = wgt + (long)ci * 9;
        #pragma unroll
        for (int co = 0; co < COUT; ++co) {
            const float* w9 = wp + (long)co * CIN * 9;
            #pragma unroll
            for (int k = 0; k < 9; ++k) acc[co] = fmaf(w9[k], vv[k], acc[co]);
        }
        __syncthreads();
    }

    const long pix = (long)oy * W + ox;
    #pragma unroll
    for (int co = 0; co < COUT; ++co) {
        float v = acc[co];
        if (RESID) v += resid[(long)n * resid_stride + (long)co * H * W + pix];
        if (LRELU) v = lrelu_f(v);
        out[(long)n * out_stride + (long)co * H * W + pix] = v;
    }
}

// ---------------------------------------------------------------------------
// Fused deformable attention: softmax(aw) + offset+flow + bilinear(zero-pad)
// gather from v + weighted sum -> out (b, 32, H, W)
// ---------------------------------------------------------------------------
__global__ __launch_bounds__(256) void deform_kernel(
    const float* __restrict__ v, const float* __restrict__ off,
    const float* __restrict__ aw, const float* __restrict__ ff,
    const float* __restrict__ fb, float* __restrict__ out, int H, int W)
{
    const int HW = H * W;
    int q = blockIdx.x * 256 + threadIdx.x;
    if (q >= HW) return;
    int m = blockIdx.y & 3;
    int b = blockIdx.y >> 2;
    int x = q % W, y = q / W;

    // softmax over L*P = 12
    float a[12];
    float mx = -1e30f;
    #pragma unroll
    for (int i = 0; i < 12; ++i) {
        a[i] = aw[((long)b * 48 + m * 12 + i) * HW + q];
        mx = fmaxf(mx, a[i]);
    }
    float s = 0.f;
    #pragma unroll
    for (int i = 0; i < 12; ++i) { a[i] = expf(a[i] - mx); s += a[i]; }
    float inv = 1.f / s;

    float o[8] = {0, 0, 0, 0, 0, 0, 0, 0};
    #pragma unroll
    for (int l = 0; l < 3; ++l) {
        float fx = 0.f, fy = 0.f;
        if (l == 0) {
            fx = fb[((long)(b * 2 + 0) * 2 + 0) * HW + q];
            fy = fb[((long)(b * 2 + 0) * 2 + 1) * HW + q];
        } else if (l == 2) {
            fx = ff[((long)(b * 2 + 1) * 2 + 0) * HW + q];
            fy = ff[((long)(b * 2 + 1) * 2 + 1) * HW + q];
        }
        const float* img = v + ((long)(b * 3 + l) * 32 + m * 8) * HW;
        #pragma unroll
        for (int p = 0; p < 4; ++p) {
            int oc = ((m * 3 + l) * 4 + p) * 2;
            // gx = loc_x*W - 0.5 == x + off_x + flow_x  (exact algebra)
            float gx = (float)x + off[((long)b * 96 + oc) * HW + q] + fx;
            float gy = (float)y + off[((long)b * 96 + oc + 1) * HW + q] + fy;
            float wgt = a[l * 4 + p] * inv;
            float x0f = floorf(gx), y0f = floorf(gy);
            float wx = gx - x0f, wy = gy - y0f;
            int x0 = (int)x0f, y0 = (int)y0f;
            #pragma unroll
            for (int t_ = 0; t_ < 4; ++t_) {
                int xi = x0 + (t_ & 1), yi = y0 + (t_ >> 1);
                float wt = ((t_ & 1) ? wx : 1.f - wx) * ((t_ >> 1) ? wy : 1.f - wy) * wgt;
                if (xi >= 0 && xi < W && yi >= 0 && yi < H) {
                    const float* pp = img + (long)yi * W + xi;
                    #pragma unroll
                    for (int d = 0; d < 8; ++d) o[d] = fmaf(wt, pp[(long)d * HW], o[d]);
                }
            }
        }
    }
    #pragma unroll
    for (int d = 0; d < 8; ++d)
        out[((long)b * 32 + m * 8 + d) * HW + q] = o[d];
}

// ---------------------------------------------------------------------------
// 1x1 conv (32->32) + lrelu
// ---------------------------------------------------------------------------
__global__ __launch_bounds__(256) void conv1x1_kernel(
    const float* __restrict__ in, const float* __restrict__ w,
    const float* __restrict__ bias, float* __restrict__ out, int HW)
{
    int q = blockIdx.x * 256 + threadIdx.x;
    if (q >= HW) return;
    long b = blockIdx.y;
    const float* ib = in + b * 32 * HW;
    float v[32];
    #pragma unroll
    for (int ci = 0; ci < 32; ++ci) v[ci] = ib[(long)ci * HW + q];
    float* ob = out + b * 32 * HW;
    #pragma unroll
    for (int co = 0; co < 32; ++co) {
        float acc = bias[co];
        #pragma unroll
        for (int ci = 0; ci < 32; ++ci) acc = fmaf(w[co * 32 + ci], v[ci], acc);
        ob[(long)co * HW + q] = lrelu_f(acc);
    }
}

// ---------------------------------------------------------------------------
extern "C" void kernel_launch(void* const* d_in, const int* in_sizes, int n_in,
                              void* d_out, int out_size, void* d_ws, size_t ws_size,
                              hipStream_t stream)
{
    (void)in_sizes; (void)n_in; (void)out_size; (void)ws_size;
    const int H = 256, W = 256, HW = H * W, B = 2;

    const float* frame    = (const float*)d_in[0];
    const float* srcframe = (const float*)d_in[1];
    const float* ff       = (const float*)d_in[2];
    const float* fb       = (const float*)d_in[3];
    const float* emb_qk_w = (const float*)d_in[4];
    const float* emb_qk_b = (const float*)d_in[5];
    const float* emb_v_w  = (const float*)d_in[6];
    const float* emb_v_b  = (const float*)d_in[7];
    const float* so_w     = (const float*)d_in[8];
    const float* so_b     = (const float*)d_in[9];
    const float* aw_w     = (const float*)d_in[10];
    const float* aw_b     = (const float*)d_in[11];
    const float* vp_w     = (const float*)d_in[12];
    const float* vp_b     = (const float*)d_in[13];
    const float* op_w     = (const float*)d_in[14];
    const float* op_b     = (const float*)d_in[15];
    const float* ff_w     = (const float*)d_in[16];
    const float* ff_b     = (const float*)d_in[17];
    const float* ffn1_w   = (const float*)d_in[18];
    const float* ffn1_b   = (const float*)d_in[19];
    const float* ffn2_w   = (const float*)d_in[20];
    const float* ffn2_b   = (const float*)d_in[21];
    const float* fus_w    = (const float*)d_in[22];
    const float* fus_b    = (const float*)d_in[23];

    float* ws = (float*)d_ws;
    // region layout (floats):
    float* A  = ws;                 // q_in (2*100*HW) -> off (2*96*HW) -> out2 -> out4
    float* Bq = ws + 13107200L;     // query (2*96*HW) -> ffn
    float* C  = ws + 25690112L;     // value (2*96*HW) -> aw (2*48*HW) + out1 -> out3
    float* D  = ws + 38273024L;     // v (2*3*32*HW)

    dim3 blk(256);
    const int tilesX = W / TILE;            // 16
    dim3 convGrid(tilesX * (H / TILE), B);  // 256 tiles x batch

    // 1. q_in
    build_qin_kernel<<<dim3(HW / 256, B), blk, 0, stream>>>(frame, ff, fb, A, H, W);

    // 2. query = lrelu(conv(q_in, emb_qk))
    conv3x3_kernel<100, 96, 1, true, false, false><<<convGrid, blk, 0, stream>>>(
        A, 100L * HW, nullptr, 0, emb_qk_w, emb_qk_b, nullptr, 0, Bq, 96L * HW, H, W, tilesX);

    // 3. value = lrelu(conv(frame (b,96,h,w), emb_v))
    conv3x3_kernel<96, 96, 1, true, false, false><<<convGrid, blk, 0, stream>>>(
        frame, 96L * HW, nullptr, 0, emb_v_w, emb_v_b, nullptr, 0, C, 96L * HW, H, W, tilesX);

    // 4. v = conv(value as 6 images of 32ch, vp)
    conv3x3_kernel<32, 32, 1, false, false, false><<<dim3(256, 6), blk, 0, stream>>>(
        C, 32L * HW, nullptr, 0, vp_w, vp_b, nullptr, 0, D, 32L * HW, H, W, tilesX);

    // 5. off = conv(query, so)
    conv3x3_kernel<96, 96, 1, false, false, false><<<convGrid, blk, 0, stream>>>(
        Bq, 96L * HW, nullptr, 0, so_w, so_b, nullptr, 0, A, 96L * HW, H, W, tilesX);

    // 6. aw = conv(query, aw_w)
    conv3x3_kernel<96, 48, 1, false, false, false><<<convGrid, blk, 0, stream>>>(
        Bq, 96L * HW, nullptr, 0, aw_w, aw_b, nullptr, 0, C, 48L * HW, H, W, tilesX);

    // 7. out1 = deformable attention (b,32,HW)
    float* out1 = C + 6291456L;
    deform_kernel<<<dim3(HW / 256, 4 * B), blk, 0, stream>>>(D, A, C, ff, fb, out1, H, W);

    // 8. out2 = conv(out1, op)
    float* out2 = A;
    conv3x3_kernel<32, 32, 1, false, false, false><<<convGrid, blk, 0, stream>>>(
        out1, 32L * HW, nullptr, 0, op_w, op_b, nullptr, 0, out2, 32L * HW, H, W, tilesX);

    // 9. out3 = conv(out2, ff_w) + frame[:,1]
    float* out3 = C;
    conv3x3_kernel<32, 32, 1, false, true, false><<<convGrid, blk, 0, stream>>>(
        out2, 32L * HW, nullptr, 0, ff_w, ff_b, frame + 32L * HW, 96L * HW, out3, 32L * HW, H, W, tilesX);

    // 10. ffn = lrelu(conv_dil2(concat(out3, srcframe[:,1]), ffn1))
    float* ffn = Bq;
    conv3x3_kernel<64, 32, 2, true, false, true><<<convGrid, blk, 0, stream>>>(
        out3, 32L * HW, srcframe + 32L * HW, 96L * HW, ffn1_w, ffn1_b, nullptr, 0, ffn, 32L * HW, H, W, tilesX);

    // 11. out4 = out3 + conv(ffn, ffn2)
    float* out4 = A;
    conv3x3_kernel<32, 32, 1, false, true, false><<<convGrid, blk, 0, stream>>>(
        ffn, 32L * HW, nullptr, 0, ffn2_w, ffn2_b, out3, 32L * HW, out4, 32L * HW, H, W, tilesX);

    // 12. d_out = lrelu(conv1x1(out4, fus))
    conv1x1_kernel<<<dim3(HW / 256, B), blk, 0, stream>>>(out4, fus_w, fus_b, (float*)d_out, HW);
}

// Round 2
// 3110.283 us; speedup vs baseline: 1.5170x; 1.5170x over previous
//
#include <hip/hip_runtime.h>
#include <cmath>

#define TILE 16

__device__ __forceinline__ float lrelu_f(float v) { return v >= 0.f ? v : 0.1f * v; }

// ---------------------------------------------------------------------------
// Build q_in = concat([warp(frame0, fb0), frame1, warp(frame2, ff1), ff1, fb0])
// q_in: (b, 100, H, W)
// ---------------------------------------------------------------------------
__global__ __launch_bounds__(256) void build_qin_kernel(
    const float* __restrict__ frame, const float* __restrict__ ff,
    const float* __restrict__ fb, float* __restrict__ qin, int H, int W)
{
    const int HW = H * W;
    int q = blockIdx.x * 256 + threadIdx.x;
    if (q >= HW) return;
    int b = blockIdx.y;
    int x = q % W, y = q / W;
    const long fbase = (long)b * 96 * HW;
    const long qbase = (long)b * 100 * HW;

    float fb0x = fb[((long)(b * 2 + 0) * 2 + 0) * HW + q];
    float fb0y = fb[((long)(b * 2 + 0) * 2 + 1) * HW + q];
    float ff1x = ff[((long)(b * 2 + 1) * 2 + 0) * HW + q];
    float ff1y = ff[((long)(b * 2 + 1) * 2 + 1) * HW + q];

    {
        float gx = (float)x + fb0x, gy = (float)y + fb0y;
        float x0f = floorf(gx), y0f = floorf(gy);
        float wx = gx - x0f, wy = gy - y0f;
        int x0 = min(max((int)x0f, 0), W - 1);
        int x1 = min(max((int)x0f + 1, 0), W - 1);
        int y0 = min(max((int)y0f, 0), H - 1);
        int y1 = min(max((int)y0f + 1, 0), H - 1);
        float w00 = (1.f - wx) * (1.f - wy), w10 = wx * (1.f - wy);
        float w01 = (1.f - wx) * wy, w11 = wx * wy;
        const float* img = frame + fbase;  // t = 0
        #pragma unroll 4
        for (int ch = 0; ch < 32; ++ch) {
            const float* p = img + (long)ch * HW;
            float v = p[y0 * W + x0] * w00 + p[y0 * W + x1] * w10 +
                      p[y1 * W + x0] * w01 + p[y1 * W + x1] * w11;
            qin[qbase + (long)ch * HW + q] = v;
        }
    }
    #pragma unroll 4
    for (int ch = 0; ch < 32; ++ch)
        qin[qbase + (long)(32 + ch) * HW + q] = frame[fbase + (long)(32 + ch) * HW + q];
    {
        float gx = (float)x + ff1x, gy = (float)y + ff1y;
        float x0f = floorf(gx), y0f = floorf(gy);
        float wx = gx - x0f, wy = gy - y0f;
        int x0 = min(max((int)x0f, 0), W - 1);
        int x1 = min(max((int)x0f + 1, 0), W - 1);
        int y0 = min(max((int)y0f, 0), H - 1);
        int y1 = min(max((int)y0f + 1, 0), H - 1);
        float w00 = (1.f - wx) * (1.f - wy), w10 = wx * (1.f - wy);
        float w01 = (1.f - wx) * wy, w11 = wx * wy;
        const float* img = frame + fbase + (long)64 * HW;  // t = 2
        #pragma unroll 4
        for (int ch = 0; ch < 32; ++ch) {
            const float* p = img + (long)ch * HW;
            float v = p[y0 * W + x0] * w00 + p[y0 * W + x1] * w10 +
                      p[y1 * W + x0] * w01 + p[y1 * W + x1] * w11;
            qin[qbase + (long)(64 + ch) * HW + q] = v;
        }
    }
    qin[qbase + 96L * HW + q] = ff1x;
    qin[qbase + 97L * HW + q] = ff1y;
    qin[qbase + 98L * HW + q] = fb0x;
    qin[qbase + 99L * HW + q] = fb0y;
}

// ---------------------------------------------------------------------------
// Direct 3x3 conv v2 (cross-correlation, zero pad = DIL, dilation = DIL).
// Block: 256 threads = 4 waves. Tile: 16x16 output pixels.
// Wave w owns COUT/4 output channels; lane owns 4 adjacent pixels (x-dir).
// Per barrier phase: CB=2 input channels staged into LDS (padded stride);
// weights read via wave-uniform scalar loads, reused across 4 pixels.
// ---------------------------------------------------------------------------
template <int CIN, int COUT, int DIL, bool LRELU, bool RESID, bool TWO_IN>
__global__ __launch_bounds__(256) void conv3x3_v2(
    const float* __restrict__ in0, long in0_stride,
    const float* __restrict__ in1, long in1_stride,
    const float* __restrict__ wgt, const float* __restrict__ bias,
    const float* __restrict__ resid, long resid_stride,
    float* __restrict__ out, long out_stride,
    int H, int W, int tilesX)
{
    constexpr int CB = 2;
    constexpr int S = TILE + 2 * DIL;      // staged tile side
    constexpr int SP = S + 1;              // padded LDS stride (odd -> spreads banks)
    constexpr int CO_W = COUT / 4;         // channels per wave
    constexpr int COLS = 4 + 2 * DIL;      // input cols needed per 4-pixel group
    __shared__ float smem[CB * S * SP];

    const int n = blockIdx.y;
    const int tx = blockIdx.x % tilesX, ty = blockIdx.x / tilesX;
    const int wv = __builtin_amdgcn_readfirstlane(threadIdx.x >> 6);  // force SGPR
    const int lane = threadIdx.x & 63;
    const int r = lane >> 2;        // 0..15 tile row
    const int g = lane & 3;         // 0..3  4-pixel group
    const int co0 = wv * CO_W;

    float acc[CO_W][4];
    #pragma unroll
    for (int co = 0; co < CO_W; ++co) {
        float bv = bias[co0 + co];
        #pragma unroll
        for (int p = 0; p < 4; ++p) acc[co][p] = bv;
    }

    const float* ib0 = in0 + (long)n * in0_stride;
    const float* ib1 = TWO_IN ? (in1 + (long)n * in1_stride) : nullptr;
    const int gy0 = ty * TILE - DIL, gx0 = tx * TILE - DIL;

    for (int ci0 = 0; ci0 < CIN; ci0 += CB) {
        // ---- stage CB channels (S x S valid, stride SP) ----
        for (int i = threadIdx.x; i < CB * S * S; i += 256) {
            int cc = i / (S * S);
            int rem = i - cc * S * S;
            int sy = rem / S, sx = rem - sy * S;
            int ci = ci0 + cc;
            const float* src = (TWO_IN && ci >= CIN / 2)
                                   ? ib1 + (long)(ci - CIN / 2) * H * W
                                   : ib0 + (long)ci * H * W;
            int gy = gy0 + sy, gx = gx0 + sx;
            float v = (gy >= 0 && gy < H && gx >= 0 && gx < W) ? src[(long)gy * W + gx] : 0.f;
            smem[cc * S * SP + sy * SP + sx] = v;
        }
        __syncthreads();

        #pragma unroll
        for (int cc = 0; cc < CB; ++cc) {
            const int ci = ci0 + cc;
            // input window for this lane's 4 pixels: 3 rows x COLS cols
            float vv[3][COLS];
            const float* sp = &smem[cc * S * SP + r * SP + g * 4];
            #pragma unroll
            for (int dy = 0; dy < 3; ++dy)
                #pragma unroll
                for (int j = 0; j < COLS; ++j)
                    vv[dy][j] = sp[dy * DIL * SP + j];

            const float* wb = wgt + ((long)co0 * CIN + ci) * 9;  // scalar base
            #pragma unroll
            for (int co = 0; co < CO_W; ++co) {
                const float* w9 = wb + (long)co * CIN * 9;       // wave-uniform
                float w0 = w9[0], w1 = w9[1], w2 = w9[2];
                float w3 = w9[3], w4 = w9[4], w5 = w9[5];
                float w6 = w9[6], w7 = w9[7], w8 = w9[8];
                #pragma unroll
                for (int p = 0; p < 4; ++p) {
                    float s = acc[co][p];
                    s = fmaf(w0, vv[0][p], s);
                    s = fmaf(w1, vv[0][p + DIL], s);
                    s = fmaf(w2, vv[0][p + 2 * DIL], s);
                    s = fmaf(w3, vv[1][p], s);
                    s = fmaf(w4, vv[1][p + DIL], s);
                    s = fmaf(w5, vv[1][p + 2 * DIL], s);
                    s = fmaf(w6, vv[2][p], s);
                    s = fmaf(w7, vv[2][p + DIL], s);
                    s = fmaf(w8, vv[2][p + 2 * DIL], s);
                    acc[co][p] = s;
                }
            }
        }
        __syncthreads();
    }

    // ---- epilogue: float4 stores ----
    const int oy = ty * TILE + r, ox = tx * TILE + g * 4;
    const long pix = (long)oy * W + ox;
    #pragma unroll
    for (int co = 0; co < CO_W; ++co) {
        float4 v = make_float4(acc[co][0], acc[co][1], acc[co][2], acc[co][3]);
        if (RESID) {
            const float4 rs = *(const float4*)&resid[(long)n * resid_stride +
                                                     (long)(co0 + co) * H * W + pix];
            v.x += rs.x; v.y += rs.y; v.z += rs.z; v.w += rs.w;
        }
        if (LRELU) {
            v.x = lrelu_f(v.x); v.y = lrelu_f(v.y);
            v.z = lrelu_f(v.z); v.w = lrelu_f(v.w);
        }
        *(float4*)&out[(long)n * out_stride + (long)(co0 + co) * H * W + pix] = v;
    }
}

// ---------------------------------------------------------------------------
// Fused deformable attention: softmax(aw) + offset+flow + bilinear(zero-pad)
// gather from v + weighted sum -> out (b, 32, H, W)
// ---------------------------------------------------------------------------
__global__ __launch_bounds__(256) void deform_kernel(
    const float* __restrict__ v, const float* __restrict__ off,
    const float* __restrict__ aw, const float* __restrict__ ff,
    const float* __restrict__ fb, float* __restrict__ out, int H, int W)
{
    const int HW = H * W;
    int q = blockIdx.x * 256 + threadIdx.x;
    if (q >= HW) return;
    int m = blockIdx.y & 3;
    int b = blockIdx.y >> 2;
    int x = q % W, y = q / W;

    float a[12];
    float mx = -1e30f;
    #pragma unroll
    for (int i = 0; i < 12; ++i) {
        a[i] = aw[((long)b * 48 + m * 12 + i) * HW + q];
        mx = fmaxf(mx, a[i]);
    }
    float s = 0.f;
    #pragma unroll
    for (int i = 0; i < 12; ++i) { a[i] = expf(a[i] - mx); s += a[i]; }
    float inv = 1.f / s;

    float o[8] = {0, 0, 0, 0, 0, 0, 0, 0};
    #pragma unroll
    for (int l = 0; l < 3; ++l) {
        float fx = 0.f, fy = 0.f;
        if (l == 0) {
            fx = fb[((long)(b * 2 + 0) * 2 + 0) * HW + q];
            fy = fb[((long)(b * 2 + 0) * 2 + 1) * HW + q];
        } else if (l == 2) {
            fx = ff[((long)(b * 2 + 1) * 2 + 0) * HW + q];
            fy = ff[((long)(b * 2 + 1) * 2 + 1) * HW + q];
        }
        const float* img = v + ((long)(b * 3 + l) * 32 + m * 8) * HW;
        #pragma unroll
        for (int p = 0; p < 4; ++p) {
            int oc = ((m * 3 + l) * 4 + p) * 2;
            float gx = (float)x + off[((long)b * 96 + oc) * HW + q] + fx;
            float gy = (float)y + off[((long)b * 96 + oc + 1) * HW + q] + fy;
            float wgt = a[l * 4 + p] * inv;
            float x0f = floorf(gx), y0f = floorf(gy);
            float wx = gx - x0f, wy = gy - y0f;
            int x0 = (int)x0f, y0 = (int)y0f;
            #pragma unroll
            for (int t_ = 0; t_ < 4; ++t_) {
                int xi = x0 + (t_ & 1), yi = y0 + (t_ >> 1);
                float wt = ((t_ & 1) ? wx : 1.f - wx) * ((t_ >> 1) ? wy : 1.f - wy) * wgt;
                if (xi >= 0 && xi < W && yi >= 0 && yi < H) {
                    const float* pp = img + (long)yi * W + xi;
                    #pragma unroll
                    for (int d = 0; d < 8; ++d) o[d] = fmaf(wt, pp[(long)d * HW], o[d]);
                }
            }
        }
    }
    #pragma unroll
    for (int d = 0; d < 8; ++d)
        out[((long)b * 32 + m * 8 + d) * HW + q] = o[d];
}

// ---------------------------------------------------------------------------
// 1x1 conv (32->32) + lrelu
// ---------------------------------------------------------------------------
__global__ __launch_bounds__(256) void conv1x1_kernel(
    const float* __restrict__ in, const float* __restrict__ w,
    const float* __restrict__ bias, float* __restrict__ out, int HW)
{
    int q = blockIdx.x * 256 + threadIdx.x;
    if (q >= HW) return;
    long b = blockIdx.y;
    const float* ib = in + b * 32 * HW;
    float v[32];
    #pragma unroll
    for (int ci = 0; ci < 32; ++ci) v[ci] = ib[(long)ci * HW + q];
    float* ob = out + b * 32 * HW;
    #pragma unroll
    for (int co = 0; co < 32; ++co) {
        float acc = bias[co];
        #pragma unroll
        for (int ci = 0; ci < 32; ++ci) acc = fmaf(w[co * 32 + ci], v[ci], acc);
        ob[(long)co * HW + q] = lrelu_f(acc);
    }
}

// ---------------------------------------------------------------------------
extern "C" void kernel_launch(void* const* d_in, const int* in_sizes, int n_in,
                              void* d_out, int out_size, void* d_ws, size_t ws_size,
                              hipStream_t stream)
{
    (void)in_sizes; (void)n_in; (void)out_size; (void)ws_size;
    const int H = 256, W = 256, HW = H * W, B = 2;

    const float* frame    = (const float*)d_in[0];
    const float* srcframe = (const float*)d_in[1];
    const float* ff       = (const float*)d_in[2];
    const float* fb       = (const float*)d_in[3];
    const float* emb_qk_w = (const float*)d_in[4];
    const float* emb_qk_b = (const float*)d_in[5];
    const float* emb_v_w  = (const float*)d_in[6];
    const float* emb_v_b  = (const float*)d_in[7];
    const float* so_w     = (const float*)d_in[8];
    const float* so_b     = (const float*)d_in[9];
    const float* aw_w     = (const float*)d_in[10];
    const float* aw_b     = (const float*)d_in[11];
    const float* vp_w     = (const float*)d_in[12];
    const float* vp_b     = (const float*)d_in[13];
    const float* op_w     = (const float*)d_in[14];
    const float* op_b     = (const float*)d_in[15];
    const float* ff_w     = (const float*)d_in[16];
    const float* ff_b     = (const float*)d_in[17];
    const float* ffn1_w   = (const float*)d_in[18];
    const float* ffn1_b   = (const float*)d_in[19];
    const float* ffn2_w   = (const float*)d_in[20];
    const float* ffn2_b   = (const float*)d_in[21];
    const float* fus_w    = (const float*)d_in[22];
    const float* fus_b    = (const float*)d_in[23];

    float* ws = (float*)d_ws;
    float* A  = ws;                 // q_in (2*100*HW) -> off (2*96*HW) -> out2 -> out4
    float* Bq = ws + 13107200L;     // query (2*96*HW) -> ffn
    float* C  = ws + 25690112L;     // value (2*96*HW) -> aw (2*48*HW) + out1 -> out3
    float* D  = ws + 38273024L;     // v (2*3*32*HW)

    dim3 blk(256);
    const int tilesX = W / TILE;            // 16
    dim3 convGrid(tilesX * (H / TILE), B);  // 256 tiles x batch

    // 1. q_in
    build_qin_kernel<<<dim3(HW / 256, B), blk, 0, stream>>>(frame, ff, fb, A, H, W);

    // 2. query = lrelu(conv(q_in, emb_qk))
    conv3x3_v2<100, 96, 1, true, false, false><<<convGrid, blk, 0, stream>>>(
        A, 100L * HW, nullptr, 0, emb_qk_w, emb_qk_b, nullptr, 0, Bq, 96L * HW, H, W, tilesX);

    // 3. value = lrelu(conv(frame (b,96,h,w), emb_v))
    conv3x3_v2<96, 96, 1, true, false, false><<<convGrid, blk, 0, stream>>>(
        frame, 96L * HW, nullptr, 0, emb_v_w, emb_v_b, nullptr, 0, C, 96L * HW, H, W, tilesX);

    // 4. v = conv(value as 6 images of 32ch, vp)
    conv3x3_v2<32, 32, 1, false, false, false><<<dim3(256, 6), blk, 0, stream>>>(
        C, 32L * HW, nullptr, 0, vp_w, vp_b, nullptr, 0, D, 32L * HW, H, W, tilesX);

    // 5. off = conv(query, so)
    conv3x3_v2<96, 96, 1, false, false, false><<<convGrid, blk, 0, stream>>>(
        Bq, 96L * HW, nullptr, 0, so_w, so_b, nullptr, 0, A, 96L * HW, H, W, tilesX);

    // 6. aw = conv(query, aw_w)
    conv3x3_v2<96, 48, 1, false, false, false><<<convGrid, blk, 0, stream>>>(
        Bq, 96L * HW, nullptr, 0, aw_w, aw_b, nullptr, 0, C, 48L * HW, H, W, tilesX);

    // 7. out1 = deformable attention (b,32,HW)
    float* out1 = C + 6291456L;
    deform_kernel<<<dim3(HW / 256, 4 * B), blk, 0, stream>>>(D, A, C, ff, fb, out1, H, W);

    // 8. out2 = conv(out1, op)
    float* out2 = A;
    conv3x3_v2<32, 32, 1, false, false, false><<<convGrid, blk, 0, stream>>>(
        out1, 32L * HW, nullptr, 0, op_w, op_b, nullptr, 0, out2, 32L * HW, H, W, tilesX);

    // 9. out3 = conv(out2, ff_w) + frame[:,1]
    float* out3 = C;
    conv3x3_v2<32, 32, 1, false, true, false><<<convGrid, blk, 0, stream>>>(
        out2, 32L * HW, nullptr, 0, ff_w, ff_b, frame + 32L * HW, 96L * HW, out3, 32L * HW, H, W, tilesX);

    // 10. ffn = lrelu(conv_dil2(concat(out3, srcframe[:,1]), ffn1))
    float* ffn = Bq;
    conv3x3_v2<64, 32, 2, true, false, true><<<convGrid, blk, 0, stream>>>(
        out3, 32L * HW, srcframe + 32L * HW, 96L * HW, ffn1_w, ffn1_b, nullptr, 0, ffn, 32L * HW, H, W, tilesX);

    // 11. out4 = out3 + conv(ffn, ffn2)
    float* out4 = A;
    conv3x3_v2<32, 32, 1, false, true, false><<<convGrid, blk, 0, stream>>>(
        ffn, 32L * HW, nullptr, 0, ffn2_w, ffn2_b, out3, 32L * HW, out4, 32L * HW, H, W, tilesX);

    // 12. d_out = lrelu(conv1x1(out4, fus))
    conv1x1_kernel<<<dim3(HW / 256, B), blk, 0, stream>>>(out4, fus_w, fus_b, (float*)d_out, HW);
}

// Round 5
// 678.820 us; speedup vs baseline: 6.9505x; 4.5819x over previous
//
#include <hip/hip_runtime.h>
#include <cmath>

typedef _Float16 half_t;
typedef _Float16 half8 __attribute__((ext_vector_type(8)));
typedef _Float16 half4 __attribute__((ext_vector_type(4)));
typedef float floatx4 __attribute__((ext_vector_type(4)));

__device__ __forceinline__ float lrelu_f(float v) { return v >= 0.f ? v : 0.1f * v; }

// ---------------------------------------------------------------------------
// Pack conv weights (OIHW fp32) -> f16 [tap][cinblk][co][ci(32)] with zero pad
// ---------------------------------------------------------------------------
template <int CIN, int COUT>
__global__ __launch_bounds__(256) void prep_w(const float* __restrict__ w,
                                              half_t* __restrict__ o)
{
    constexpr int NCB = (CIN + 31) / 32;
    const int total = 9 * NCB * COUT * 32;
    int i = blockIdx.x * 256 + threadIdx.x;
    if (i >= total) return;
    int ci = i & 31;
    int t = i >> 5;
    int co = t % COUT; t /= COUT;
    int cb = t % NCB;
    int tap = t / NCB;
    int cg = cb * 32 + ci;
    float v = (cg < CIN) ? w[((long)co * CIN + cg) * 9 + tap] : 0.f;
    o[i] = (half_t)v;
}

// ---------------------------------------------------------------------------
// Build q_in (f16) = concat([warp(frame0, fb0), frame1, warp(frame2, ff1), ff1, fb0])
// ---------------------------------------------------------------------------
__global__ __launch_bounds__(256) void build_qin_kernel(
    const float* __restrict__ frame, const float* __restrict__ ff,
    const float* __restrict__ fb, half_t* __restrict__ qin, int H, int W)
{
    const int HW = H * W;
    int q = blockIdx.x * 256 + threadIdx.x;
    if (q >= HW) return;
    int b = blockIdx.y;
    int x = q % W, y = q / W;
    const long fbase = (long)b * 96 * HW;
    const long qbase = (long)b * 100 * HW;

    float fb0x = fb[((long)(b * 2 + 0) * 2 + 0) * HW + q];
    float fb0y = fb[((long)(b * 2 + 0) * 2 + 1) * HW + q];
    float ff1x = ff[((long)(b * 2 + 1) * 2 + 0) * HW + q];
    float ff1y = ff[((long)(b * 2 + 1) * 2 + 1) * HW + q];

    {
        float gx = (float)x + fb0x, gy = (float)y + fb0y;
        float x0f = floorf(gx), y0f = floorf(gy);
        float wx = gx - x0f, wy = gy - y0f;
        int x0 = min(max((int)x0f, 0), W - 1);
        int x1 = min(max((int)x0f + 1, 0), W - 1);
        int y0 = min(max((int)y0f, 0), H - 1);
        int y1 = min(max((int)y0f + 1, 0), H - 1);
        float w00 = (1.f - wx) * (1.f - wy), w10 = wx * (1.f - wy);
        float w01 = (1.f - wx) * wy, w11 = wx * wy;
        const float* img = frame + fbase;  // t = 0
        #pragma unroll 4
        for (int ch = 0; ch < 32; ++ch) {
            const float* p = img + (long)ch * HW;
            float v = p[y0 * W + x0] * w00 + p[y0 * W + x1] * w10 +
                      p[y1 * W + x0] * w01 + p[y1 * W + x1] * w11;
            qin[qbase + (long)ch * HW + q] = (half_t)v;
        }
    }
    #pragma unroll 4
    for (int ch = 0; ch < 32; ++ch)
        qin[qbase + (long)(32 + ch) * HW + q] =
            (half_t)frame[fbase + (long)(32 + ch) * HW + q];
    {
        float gx = (float)x + ff1x, gy = (float)y + ff1y;
        float x0f = floorf(gx), y0f = floorf(gy);
        float wx = gx - x0f, wy = gy - y0f;
        int x0 = min(max((int)x0f, 0), W - 1);
        int x1 = min(max((int)x0f + 1, 0), W - 1);
        int y0 = min(max((int)y0f, 0), H - 1);
        int y1 = min(max((int)y0f + 1, 0), H - 1);
        float w00 = (1.f - wx) * (1.f - wy), w10 = wx * (1.f - wy);
        float w01 = (1.f - wx) * wy, w11 = wx * wy;
        const float* img = frame + fbase + (long)64 * HW;  // t = 2
        #pragma unroll 4
        for (int ch = 0; ch < 32; ++ch) {
            const float* p = img + (long)ch * HW;
            float v = p[y0 * W + x0] * w00 + p[y0 * W + x1] * w10 +
                      p[y1 * W + x0] * w01 + p[y1 * W + x1] * w11;
            qin[qbase + (long)(64 + ch) * HW + q] = (half_t)v;
        }
    }
    qin[qbase + 96L * HW + q] = (half_t)ff1x;
    qin[qbase + 97L * HW + q] = (half_t)ff1y;
    qin[qbase + 98L * HW + q] = (half_t)fb0x;
    qin[qbase + 99L * HW + q] = (half_t)fb0y;
}

// ---------------------------------------------------------------------------
// Implicit-GEMM 3x3 conv on MFMA f16 (zero pad = DIL, dilation = DIL).
// Block: 256 thr / 4 waves; tile 16x16 px. Wave wv owns image rows wv*4..+3.
// M-frag = one row of 16 px; N = cout; K = cin blocks of 32 (zero-padded).
// A staged in LDS f16 with XOR chunk swizzle (conflict-free ds_read_b128);
// B frags straight from prepacked global f16 (L2-resident).
// RESID_MODE: 0 none, 1 fp32 planar, 2 f16 planar. OUT_CL: channel-last f16 out.
// ---------------------------------------------------------------------------
template <int CIN, int COUT, int DIL, bool LRELU, int RESID_MODE, bool TWO_IN,
          typename T0, typename T1, bool OUT_CL>
__global__ __launch_bounds__(256, 2) void conv3x3_mfma(
    const T0* __restrict__ in0, long in0_stride,
    const T1* __restrict__ in1, long in1_stride,
    const half_t* __restrict__ w16, const float* __restrict__ bias,
    const void* __restrict__ resid, long resid_stride,
    half_t* __restrict__ out, long out_stride, int H, int W)
{
    constexpr int NCB = (CIN + 31) / 32;
    constexpr int S = 16 + 2 * DIL;
    constexpr int NF = COUT / 16;
    __shared__ half_t sm[32 * S * S];

    const int n = blockIdx.y;
    const int tile = blockIdx.x;
    const int tx = tile & 15, ty = tile >> 4;   // W==256 -> 16 tiles per row
    const int tid = threadIdx.x;
    const int wv = tid >> 6, lane = tid & 63;
    const int cl = lane & 15, jk = lane >> 4;

    floatx4 acc[4][NF] = {};

    const int gy0 = ty * 16 - DIL, gx0 = tx * 16 - DIL;
    const int HWl = H * W;

    for (int cb = 0; cb < NCB; ++cb) {
        // ---- stage one 32-cin block of the (S x S) patch, fp->f16, swizzled ----
        for (int i = tid; i < 32 * S * S; i += 256) {
            int ci = i / (S * S);
            int rem = i - ci * (S * S);
            int sy = rem / S, sx = rem - sy * S;
            int cg = cb * 32 + ci;
            int gy = gy0 + sy, gx = gx0 + sx;
            float v = 0.f;
            if (cg < CIN && gy >= 0 && gy < H && gx >= 0 && gx < W) {
                if (TWO_IN && cg >= CIN / 2)
                    v = (float)in1[(long)n * in1_stride + (long)(cg - CIN / 2) * HWl + (long)gy * W + gx];
                else
                    v = (float)in0[(long)n * in0_stride + (long)cg * HWl + (long)gy * W + gx];
            }
            int pix = sy * S + sx;
            sm[(pix * 4 + ((ci >> 3) ^ ((pix >> 1) & 3))) * 8 + (ci & 7)] = (half_t)v;
        }
        __syncthreads();

        #pragma unroll
        for (int tap = 0; tap < 9; ++tap) {
            const int ky = tap / 3, kx = tap % 3;
            half8 bf[NF];
            const half_t* wb = w16 + (long)(tap * NCB + cb) * COUT * 32;
            #pragma unroll
            for (int nn = 0; nn < NF; ++nn)
                bf[nn] = *(const half8*)&wb[(nn * 16 + cl) * 32 + jk * 8];
            #pragma unroll
            for (int m = 0; m < 4; ++m) {
                int row = wv * 4 + m + ky * DIL;
                int pix = row * S + kx * DIL + cl;
                half8 af = *(const half8*)&sm[(pix * 4 + (jk ^ ((pix >> 1) & 3))) * 8];
                #pragma unroll
                for (int nn = 0; nn < NF; ++nn)
                    acc[m][nn] = __builtin_amdgcn_mfma_f32_16x16x32_f16(
                        af, bf[nn], acc[m][nn], 0, 0, 0);
            }
        }
        __syncthreads();
    }

    // ---- epilogue. C mapping: cout = nn*16 + (lane&15); px = (lane>>4)*4 + reg ----
    const int x0 = tx * 16 + jk * 4;
    #pragma unroll
    for (int m = 0; m < 4; ++m) {
        const int yy = ty * 16 + wv * 4 + m;
        #pragma unroll
        for (int nn = 0; nn < NF; ++nn) {
            const int co = nn * 16 + cl;
            float bv = bias[co];
            float r[4];
            #pragma unroll
            for (int i = 0; i < 4; ++i) r[i] = acc[m][nn][i] + bv;
            if constexpr (RESID_MODE == 1) {
                const float* rp = (const float*)resid + (long)n * resid_stride +
                                  (long)co * HWl + (long)yy * W + x0;
                float4 rv = *(const float4*)rp;
                r[0] += rv.x; r[1] += rv.y; r[2] += rv.z; r[3] += rv.w;
            } else if constexpr (RESID_MODE == 2) {
                const half_t* rp = (const half_t*)resid + (long)n * resid_stride +
                                   (long)co * HWl + (long)yy * W + x0;
                half4 rv = *(const half4*)rp;
                #pragma unroll
                for (int i = 0; i < 4; ++i) r[i] += (float)rv[i];
            }
            if (LRELU) {
                #pragma unroll
                for (int i = 0; i < 4; ++i) r[i] = lrelu_f(r[i]);
            }
            if constexpr (OUT_CL) {
                long base = (long)n * out_stride + ((long)yy * W + x0) * 32 + co;
                #pragma unroll
                for (int i = 0; i < 4; ++i) out[base + i * 32] = (half_t)r[i];
            } else {
                half4 st;
                #pragma unroll
                for (int i = 0; i < 4; ++i) st[i] = (half_t)r[i];
                *(half4*)&out[(long)n * out_stride + (long)co * HWl + (long)yy * W + x0] = st;
            }
        }
    }
}

// ---------------------------------------------------------------------------
// Fused deformable attention (f16 in/out). v is channel-last: [img][pix][32].
// ---------------------------------------------------------------------------
__global__ __launch_bounds__(256) void deform_f16(
    const half_t* __restrict__ v_cl, const half_t* __restrict__ off,
    const half_t* __restrict__ aw, const float* __restrict__ ff,
    const float* __restrict__ fb, half_t* __restrict__ out1, int H, int W)
{
    const int HW = H * W;
    int q = blockIdx.x * 256 + threadIdx.x;
    if (q >= HW) return;
    int m = blockIdx.y & 3;
    int b = blockIdx.y >> 2;
    int x = q % W, y = q / W;

    float a[12];
    float mx = -1e30f;
    #pragma unroll
    for (int i = 0; i < 12; ++i) {
        a[i] = (float)aw[((long)b * 48 + m * 12 + i) * HW + q];
        mx = fmaxf(mx, a[i]);
    }
    float s = 0.f;
    #pragma unroll
    for (int i = 0; i < 12; ++i) { a[i] = expf(a[i] - mx); s += a[i]; }
    float inv = 1.f / s;

    float o[8] = {0, 0, 0, 0, 0, 0, 0, 0};
    #pragma unroll
    for (int l = 0; l < 3; ++l) {
        float fx = 0.f, fy = 0.f;
        if (l == 0) {
            fx = fb[((long)(b * 2 + 0) * 2 + 0) * HW + q];
            fy = fb[((long)(b * 2 + 0) * 2 + 1) * HW + q];
        } else if (l == 2) {
            fx = ff[((long)(b * 2 + 1) * 2 + 0) * HW + q];
            fy = ff[((long)(b * 2 + 1) * 2 + 1) * HW + q];
        }
        const long ibase = (long)(b * 3 + l) * HW * 32 + m * 8;
        #pragma unroll
        for (int p = 0; p < 4; ++p) {
            int oc = ((m * 3 + l) * 4 + p) * 2;
            float gx = (float)x + (float)off[((long)b * 96 + oc) * HW + q] + fx;
            float gy = (float)y + (float)off[((long)b * 96 + oc + 1) * HW + q] + fy;
            float wgt = a[l * 4 + p] * inv;
            float x0f = floorf(gx), y0f = floorf(gy);
            float wx = gx - x0f, wy = gy - y0f;
            int x0 = (int)x0f, y0 = (int)y0f;
            #pragma unroll
            for (int t_ = 0; t_ < 4; ++t_) {
                int xi = x0 + (t_ & 1), yi = y0 + (t_ >> 1);
                float wt = ((t_ & 1) ? wx : 1.f - wx) * ((t_ >> 1) ? wy : 1.f - wy) * wgt;
                if (xi >= 0 && xi < W && yi >= 0 && yi < H) {
                    const half8 vv = *(const half8*)&v_cl[ibase + (long)(yi * W + xi) * 32];
                    #pragma unroll
                    for (int d = 0; d < 8; ++d) o[d] = fmaf(wt, (float)vv[d], o[d]);
                }
            }
        }
    }
    #pragma unroll
    for (int d = 0; d < 8; ++d)
        out1[((long)b * 32 + m * 8 + d) * HW + q] = (half_t)o[d];
}

// ---------------------------------------------------------------------------
// 1x1 conv (32->32) + lrelu, f16 in, fp32 out (final)
// ---------------------------------------------------------------------------
__global__ __launch_bounds__(256) void conv1x1_f16(
    const half_t* __restrict__ in, const float* __restrict__ w,
    const float* __restrict__ bias, float* __restrict__ out, int HW)
{
    int q = blockIdx.x * 256 + threadIdx.x;
    if (q >= HW) return;
    long b = blockIdx.y;
    const half_t* ib = in + b * 32 * HW;
    float v[32];
    #pragma unroll
    for (int ci = 0; ci < 32; ++ci) v[ci] = (float)ib[(long)ci * HW + q];
    float* ob = out + b * 32 * HW;
    #pragma unroll
    for (int co = 0; co < 32; ++co) {
        float acc = bias[co];
        #pragma unroll
        for (int ci = 0; ci < 32; ++ci) acc = fmaf(w[co * 32 + ci], v[ci], acc);
        ob[(long)co * HW + q] = lrelu_f(acc);
    }
}

// ---------------------------------------------------------------------------
extern "C" void kernel_launch(void* const* d_in, const int* in_sizes, int n_in,
                              void* d_out, int out_size, void* d_ws, size_t ws_size,
                              hipStream_t stream)
{
    (void)in_sizes; (void)n_in; (void)out_size; (void)ws_size;
    const int H = 256, W = 256, HW = H * W, B = 2;

    const float* frame    = (const float*)d_in[0];
    const float* srcframe = (const float*)d_in[1];
    const float* ff       = (const float*)d_in[2];
    const float* fb       = (const float*)d_in[3];
    const float* emb_qk_w = (const float*)d_in[4];
    const float* emb_qk_b = (const float*)d_in[5];
    const float* emb_v_w  = (const float*)d_in[6];
    const float* emb_v_b  = (const float*)d_in[7];
    const float* so_w     = (const float*)d_in[8];
    const float* so_b     = (const float*)d_in[9];
    const float* aw_w     = (const float*)d_in[10];
    const float* aw_b     = (const float*)d_in[11];
    const float* vp_w     = (const float*)d_in[12];
    const float* vp_b     = (const float*)d_in[13];
    const float* op_w     = (const float*)d_in[14];
    const float* op_b     = (const float*)d_in[15];
    const float* ff_w     = (const float*)d_in[16];
    const float* ff_b     = (const float*)d_in[17];
    const float* ffn1_w   = (const float*)d_in[18];
    const float* ffn1_b   = (const float*)d_in[19];
    const float* ffn2_w   = (const float*)d_in[20];
    const float* ffn2_b   = (const float*)d_in[21];
    const float* fus_w    = (const float*)d_in[22];
    const float* fus_b    = (const float*)d_in[23];

    half_t* hw = (half_t*)d_ws;
    half_t* q_in16  = hw;                  // 2*100*HW
    half_t* query16 = hw + 13107200L;      // 2*96*HW
    half_t* value16 = hw + 25690112L;      // 2*96*HW
    half_t* v_cl    = hw + 38273024L;      // 6*HW*32 channel-last
    half_t* off16   = hw + 50855936L;      // 2*96*HW
    half_t* aw16    = hw + 63438848L;      // 2*48*HW
    half_t* out1    = hw + 69730304L;      // 2*32*HW
    half_t* out2    = hw + 73924608L;
    half_t* out3    = hw + 78118912L;
    half_t* ffnb    = hw + 82313216L;
    half_t* out4    = hw + 86507520L;
    half_t* wq      = hw + 90701824L;      // 9*4*96*32
    half_t* wv      = hw + 90812416L;      // 9*3*96*32
    half_t* wso     = hw + 90895360L;
    half_t* waw     = hw + 90978304L;      // 9*3*48*32
    half_t* wvp     = hw + 91019776L;      // 9*1*32*32
    half_t* wop     = hw + 91028992L;
    half_t* wff     = hw + 91038208L;
    half_t* wffn1   = hw + 91047424L;      // 9*2*32*32
    half_t* wffn2   = hw + 91065856L;

    dim3 blk(256);

    // ---- weight packing ----
    prep_w<100, 96><<<(9 * 4 * 96 * 32 + 255) / 256, blk, 0, stream>>>(emb_qk_w, wq);
    prep_w<96, 96><<<(9 * 3 * 96 * 32 + 255) / 256, blk, 0, stream>>>(emb_v_w, wv);
    prep_w<96, 96><<<(9 * 3 * 96 * 32 + 255) / 256, blk, 0, stream>>>(so_w, wso);
    prep_w<96, 48><<<(9 * 3 * 48 * 32 + 255) / 256, blk, 0, stream>>>(aw_w, waw);
    prep_w<32, 32><<<(9 * 1 * 32 * 32 + 255) / 256, blk, 0, stream>>>(vp_w, wvp);
    prep_w<32, 32><<<(9 * 1 * 32 * 32 + 255) / 256, blk, 0, stream>>>(op_w, wop);
    prep_w<32, 32><<<(9 * 1 * 32 * 32 + 255) / 256, blk, 0, stream>>>(ff_w, wff);
    prep_w<64, 32><<<(9 * 2 * 32 * 32 + 255) / 256, blk, 0, stream>>>(ffn1_w, wffn1);
    prep_w<32, 32><<<(9 * 1 * 32 * 32 + 255) / 256, blk, 0, stream>>>(ffn2_w, wffn2);

    // ---- q_in ----
    build_qin_kernel<<<dim3(HW / 256, B), blk, 0, stream>>>(frame, ff, fb, q_in16, H, W);

    dim3 convGrid(256, B);

    // query = lrelu(conv(q_in, emb_qk))
    conv3x3_mfma<100, 96, 1, true, 0, false, half_t, half_t, false>
        <<<convGrid, blk, 0, stream>>>(q_in16, 100L * HW, nullptr, 0, wq, emb_qk_b,
                                       nullptr, 0, query16, 96L * HW, H, W);
    // value = lrelu(conv(frame, emb_v))
    conv3x3_mfma<96, 96, 1, true, 0, false, float, float, false>
        <<<convGrid, blk, 0, stream>>>(frame, 96L * HW, nullptr, 0, wv, emb_v_b,
                                       nullptr, 0, value16, 96L * HW, H, W);
    // v = conv(value as 6x32ch, vp) -> channel-last
    conv3x3_mfma<32, 32, 1, false, 0, false, half_t, half_t, true>
        <<<dim3(256, 6), blk, 0, stream>>>(value16, 32L * HW, nullptr, 0, wvp, vp_b,
                                           nullptr, 0, v_cl, (long)HW * 32, H, W);
    // off = conv(query, so)
    conv3x3_mfma<96, 96, 1, false, 0, false, half_t, half_t, false>
        <<<convGrid, blk, 0, stream>>>(query16, 96L * HW, nullptr, 0, wso, so_b,
                                       nullptr, 0, off16, 96L * HW, H, W);
    // aw = conv(query, aw_w)
    conv3x3_mfma<96, 48, 1, false, 0, false, half_t, half_t, false>
        <<<convGrid, blk, 0, stream>>>(query16, 96L * HW, nullptr, 0, waw, aw_b,
                                       nullptr, 0, aw16, 48L * HW, H, W);
    // out1 = deformable attention
    deform_f16<<<dim3(HW / 256, 4 * B), blk, 0, stream>>>(v_cl, off16, aw16, ff, fb,
                                                          out1, H, W);
    // out2 = conv(out1, op)
    conv3x3_mfma<32, 32, 1, false, 0, false, half_t, half_t, false>
        <<<convGrid, blk, 0, stream>>>(out1, 32L * HW, nullptr, 0, wop, op_b,
                                       nullptr, 0, out2, 32L * HW, H, W);
    // out3 = conv(out2, ff_w) + frame[:,1]
    conv3x3_mfma<32, 32, 1, false, 1, false, half_t, half_t, false>
        <<<convGrid, blk, 0, stream>>>(out2, 32L * HW, nullptr, 0, wff, ff_b,
                                       frame + 32L * HW, 96L * HW, out3, 32L * HW, H, W);
    // ffn = lrelu(conv_dil2(concat(out3, srcframe[:,1]), ffn1))
    conv3x3_mfma<64, 32, 2, true, 0, true, half_t, float, false>
        <<<convGrid, blk, 0, stream>>>(out3, 32L * HW, srcframe + 32L * HW, 96L * HW,
                                       wffn1, ffn1_b, nullptr, 0, ffnb, 32L * HW, H, W);
    // out4 = out3 + conv(ffn, ffn2)
    conv3x3_mfma<32, 32, 1, false, 2, false, half_t, half_t, false>
        <<<convGrid, blk, 0, stream>>>(ffnb, 32L * HW, nullptr, 0, wffn2, ffn2_b,
                                       out3, 32L * HW, out4, 32L * HW, H, W);
    // d_out = lrelu(conv1x1(out4, fus))
    conv1x1_f16<<<dim3(HW / 256, B), blk, 0, stream>>>(out4, fus_w, fus_b,
                                                       (float*)d_out, HW);
}

// Round 7
// 597.989 us; speedup vs baseline: 7.8900x; 1.1352x over previous
//
#include <hip/hip_runtime.h>
#include <cmath>

typedef _Float16 half_t;
typedef _Float16 half8 __attribute__((ext_vector_type(8)));
typedef _Float16 half4 __attribute__((ext_vector_type(4)));
typedef float floatx4 __attribute__((ext_vector_type(4)));

__device__ __forceinline__ float lrelu_f(float v) { return v >= 0.f ? v : 0.1f * v; }

// ---------------------------------------------------------------------------
// Pack conv weights (OIHW fp32) -> f16 [tap][cinblk][co_total][ci(32)], with
// the co range [co_off, co_off+co_n) taken from this source tensor.
// ---------------------------------------------------------------------------
template <int CIN, int COTOT>
__global__ __launch_bounds__(256) void prep_w_cat(const float* __restrict__ w,
                                                  half_t* __restrict__ o,
                                                  int co_off, int co_n)
{
    constexpr int NCB = (CIN + 31) / 32;
    const int total = 9 * NCB * co_n * 32;
    int i = blockIdx.x * 256 + threadIdx.x;
    if (i >= total) return;
    int ci = i & 31;
    int t = i >> 5;
    int col = t % co_n; t /= co_n;
    int cb = t % NCB;
    int tap = t / NCB;
    int cg = cb * 32 + ci;
    float v = (cg < CIN) ? w[((long)col * CIN + cg) * 9 + tap] : 0.f;
    o[(((long)tap * NCB + cb) * COTOT + co_off + col) * 32 + ci] = (half_t)v;
}

// ---------------------------------------------------------------------------
// Build q_in (f16) = concat([warp(frame0, fb0), frame1, warp(frame2, ff1), ff1, fb0])
// ---------------------------------------------------------------------------
__global__ __launch_bounds__(256) void build_qin_kernel(
    const float* __restrict__ frame, const float* __restrict__ ff,
    const float* __restrict__ fb, half_t* __restrict__ qin, int H, int W)
{
    const int HW = H * W;
    int q = blockIdx.x * 256 + threadIdx.x;
    if (q >= HW) return;
    int b = blockIdx.y;
    int x = q % W, y = q / W;
    const long fbase = (long)b * 96 * HW;
    const long qbase = (long)b * 100 * HW;

    float fb0x = fb[((long)(b * 2 + 0) * 2 + 0) * HW + q];
    float fb0y = fb[((long)(b * 2 + 0) * 2 + 1) * HW + q];
    float ff1x = ff[((long)(b * 2 + 1) * 2 + 0) * HW + q];
    float ff1y = ff[((long)(b * 2 + 1) * 2 + 1) * HW + q];

    {
        float gx = (float)x + fb0x, gy = (float)y + fb0y;
        float x0f = floorf(gx), y0f = floorf(gy);
        float wx = gx - x0f, wy = gy - y0f;
        int x0 = min(max((int)x0f, 0), W - 1);
        int x1 = min(max((int)x0f + 1, 0), W - 1);
        int y0 = min(max((int)y0f, 0), H - 1);
        int y1 = min(max((int)y0f + 1, 0), H - 1);
        float w00 = (1.f - wx) * (1.f - wy), w10 = wx * (1.f - wy);
        float w01 = (1.f - wx) * wy, w11 = wx * wy;
        const float* img = frame + fbase;  // t = 0
        #pragma unroll 4
        for (int ch = 0; ch < 32; ++ch) {
            const float* p = img + (long)ch * HW;
            float v = p[y0 * W + x0] * w00 + p[y0 * W + x1] * w10 +
                      p[y1 * W + x0] * w01 + p[y1 * W + x1] * w11;
            qin[qbase + (long)ch * HW + q] = (half_t)v;
        }
    }
    #pragma unroll 4
    for (int ch = 0; ch < 32; ++ch)
        qin[qbase + (long)(32 + ch) * HW + q] =
            (half_t)frame[fbase + (long)(32 + ch) * HW + q];
    {
        float gx = (float)x + ff1x, gy = (float)y + ff1y;
        float x0f = floorf(gx), y0f = floorf(gy);
        float wx = gx - x0f, wy = gy - y0f;
        int x0 = min(max((int)x0f, 0), W - 1);
        int x1 = min(max((int)x0f + 1, 0), W - 1);
        int y0 = min(max((int)y0f, 0), H - 1);
        int y1 = min(max((int)y0f + 1, 0), H - 1);
        float w00 = (1.f - wx) * (1.f - wy), w10 = wx * (1.f - wy);
        float w01 = (1.f - wx) * wy, w11 = wx * wy;
        const float* img = frame + fbase + (long)64 * HW;  // t = 2
        #pragma unroll 4
        for (int ch = 0; ch < 32; ++ch) {
            const float* p = img + (long)ch * HW;
            float v = p[y0 * W + x0] * w00 + p[y0 * W + x1] * w10 +
                      p[y1 * W + x0] * w01 + p[y1 * W + x1] * w11;
            qin[qbase + (long)(64 + ch) * HW + q] = (half_t)v;
        }
    }
    qin[qbase + 96L * HW + q] = (half_t)ff1x;
    qin[qbase + 97L * HW + q] = (half_t)ff1y;
    qin[qbase + 98L * HW + q] = (half_t)fb0x;
    qin[qbase + 99L * HW + q] = (half_t)fb0y;
}

// ---------------------------------------------------------------------------
// Implicit-GEMM 3x3 conv on MFMA f16 (zero pad = DIL, dilation = DIL).
// Block: 256 thr / 4 waves; tile 16x16 px. Wave wv owns image rows wv*4..+3.
// OUTC=0 -> planar f16 out; OUTC>0 -> channel-last record of OUTC halves.
// Bias: co < SPLIT from bias0 else bias1[co-SPLIT] (SPLIT>=COUT folds away).
// RESID_MODE: 0 none, 1 fp32 planar, 2 f16 planar.
// ---------------------------------------------------------------------------
template <int CIN, int COUT, int DIL, bool LRELU, int RESID_MODE, bool TWO_IN,
          typename T0, typename T1, int OUTC, int SPLIT>
__global__ __launch_bounds__(256, 2) void conv3x3_mfma(
    const T0* __restrict__ in0, long in0_stride,
    const T1* __restrict__ in1, long in1_stride,
    const half_t* __restrict__ w16,
    const float* __restrict__ bias0, const float* __restrict__ bias1,
    const void* __restrict__ resid, long resid_stride,
    half_t* __restrict__ out, long out_stride, int H, int W)
{
    constexpr int NCB = (CIN + 31) / 32;
    constexpr int S = 16 + 2 * DIL;
    constexpr int NF = COUT / 16;
    __shared__ half_t sm[32 * S * S];

    const int n = blockIdx.y;
    const int tile = blockIdx.x;
    const int tx = tile & 15, ty = tile >> 4;   // W==256 -> 16 tiles per row
    const int tid = threadIdx.x;
    const int wv = tid >> 6, lane = tid & 63;
    const int cl = lane & 15, jk = lane >> 4;

    floatx4 acc[4][NF] = {};

    const int gy0 = ty * 16 - DIL, gx0 = tx * 16 - DIL;
    const int HWl = H * W;

    for (int cb = 0; cb < NCB; ++cb) {
        // ---- stage one 32-cin block of the (S x S) patch, fp->f16, swizzled ----
        for (int i = tid; i < 32 * S * S; i += 256) {
            int ci = i / (S * S);
            int rem = i - ci * (S * S);
            int sy = rem / S, sx = rem - sy * S;
            int cg = cb * 32 + ci;
            int gy = gy0 + sy, gx = gx0 + sx;
            float v = 0.f;
            if (cg < CIN && gy >= 0 && gy < H && gx >= 0 && gx < W) {
                if (TWO_IN && cg >= CIN / 2)
                    v = (float)in1[(long)n * in1_stride + (long)(cg - CIN / 2) * HWl + (long)gy * W + gx];
                else
                    v = (float)in0[(long)n * in0_stride + (long)cg * HWl + (long)gy * W + gx];
            }
            int pix = sy * S + sx;
            sm[(pix * 4 + ((ci >> 3) ^ ((pix >> 1) & 3))) * 8 + (ci & 7)] = (half_t)v;
        }
        __syncthreads();

        #pragma unroll
        for (int tap = 0; tap < 9; ++tap) {
            const int ky = tap / 3, kx = tap % 3;
            half8 bf[NF];
            const half_t* wb = w16 + (long)(tap * NCB + cb) * COUT * 32;
            #pragma unroll
            for (int nn = 0; nn < NF; ++nn)
                bf[nn] = *(const half8*)&wb[(nn * 16 + cl) * 32 + jk * 8];
            #pragma unroll
            for (int m = 0; m < 4; ++m) {
                int row = wv * 4 + m + ky * DIL;
                int pix = row * S + kx * DIL + cl;
                half8 af = *(const half8*)&sm[(pix * 4 + (jk ^ ((pix >> 1) & 3))) * 8];
                #pragma unroll
                for (int nn = 0; nn < NF; ++nn)
                    acc[m][nn] = __builtin_amdgcn_mfma_f32_16x16x32_f16(
                        af, bf[nn], acc[m][nn], 0, 0, 0);
            }
        }
        __syncthreads();
    }

    // ---- epilogue. C mapping: cout = nn*16 + (lane&15); px = (lane>>4)*4 + reg ----
    const int x0 = tx * 16 + jk * 4;
    #pragma unroll
    for (int m = 0; m < 4; ++m) {
        const int yy = ty * 16 + wv * 4 + m;
        #pragma unroll
        for (int nn = 0; nn < NF; ++nn) {
            const int co = nn * 16 + cl;
            float bv = (co < SPLIT) ? bias0[co] : bias1[co - SPLIT];
            float r[4];
            #pragma unroll
            for (int i = 0; i < 4; ++i) r[i] = acc[m][nn][i] + bv;
            if constexpr (RESID_MODE == 1) {
                const float* rp = (const float*)resid + (long)n * resid_stride +
                                  (long)co * HWl + (long)yy * W + x0;
                float4 rv = *(const float4*)rp;
                r[0] += rv.x; r[1] += rv.y; r[2] += rv.z; r[3] += rv.w;
            } else if constexpr (RESID_MODE == 2) {
                const half_t* rp = (const half_t*)resid + (long)n * resid_stride +
                                   (long)co * HWl + (long)yy * W + x0;
                half4 rv = *(const half4*)rp;
                #pragma unroll
                for (int i = 0; i < 4; ++i) r[i] += (float)rv[i];
            }
            if (LRELU) {
                #pragma unroll
                for (int i = 0; i < 4; ++i) r[i] = lrelu_f(r[i]);
            }
            if constexpr (OUTC > 0) {
                long base = (long)n * out_stride + ((long)yy * W + x0) * OUTC + co;
                #pragma unroll
                for (int i = 0; i < 4; ++i) out[base + i * OUTC] = (half_t)r[i];
            } else {
                half4 st;
                #pragma unroll
                for (int i = 0; i < 4; ++i) st[i] = (half_t)r[i];
                *(half4*)&out[(long)n * out_stride + (long)co * HWl + (long)yy * W + x0] = st;
            }
        }
    }
}

// ---------------------------------------------------------------------------
// Fused deformable attention v2: 16x16 pixel tile per block, ALL 4 heads per
// thread. offaw is channel-last [b][pix][144] (96 off + 48 aw). v channel-last
// [img][pix][32]. XCD-swizzled tile order for L2 locality.
// ---------------------------------------------------------------------------
__global__ __launch_bounds__(256) void deform_v2(
    const half_t* __restrict__ v_cl, const half_t* __restrict__ offaw,
    const float* __restrict__ ff, const float* __restrict__ fb,
    half_t* __restrict__ out1, int H, int W)
{
    const int HW = H * W;
    const int bid = blockIdx.x;                 // 256 tiles
    const int swz = (bid & 7) * 32 + (bid >> 3);  // XCD k -> contiguous strip
    const int tx = swz & 15, ty = swz >> 4;
    const int b = blockIdx.y;
    const int r = threadIdx.x >> 4, c = threadIdx.x & 15;
    const int x = tx * 16 + c, y = ty * 16 + r;
    const int q = y * W + x;

    // 288B per-pixel record: off[96] + aw[48]
    const half8* rec8 = (const half8*)&offaw[((long)b * HW + q) * 144];
    half8 rec[18];
    #pragma unroll
    for (int i = 0; i < 18; ++i) rec[i] = rec8[i];

    float fbx = fb[((long)(b * 2 + 0) * 2 + 0) * HW + q];
    float fby = fb[((long)(b * 2 + 0) * 2 + 1) * HW + q];
    float ffx = ff[((long)(b * 2 + 1) * 2 + 0) * HW + q];
    float ffy = ff[((long)(b * 2 + 1) * 2 + 1) * HW + q];

    float o[32];
    #pragma unroll
    for (int i = 0; i < 32; ++i) o[i] = 0.f;

    #pragma unroll
    for (int m = 0; m < 4; ++m) {
        float a[12], mx = -1e30f;
        #pragma unroll
        for (int i = 0; i < 12; ++i) {
            int ii = 96 + m * 12 + i;
            a[i] = (float)rec[ii >> 3][ii & 7];
            mx = fmaxf(mx, a[i]);
        }
        float s = 0.f;
        #pragma unroll
        for (int i = 0; i < 12; ++i) { a[i] = expf(a[i] - mx); s += a[i]; }
        float inv = 1.f / s;

        #pragma unroll
        for (int l = 0; l < 3; ++l) {
            float fx = (l == 0) ? fbx : (l == 2) ? ffx : 0.f;
            float fy = (l == 0) ? fby : (l == 2) ? ffy : 0.f;
            const half_t* img = v_cl + (long)(b * 3 + l) * HW * 32 + m * 8;
            #pragma unroll
            for (int p = 0; p < 4; ++p) {
                int oc = ((m * 3 + l) * 4 + p) * 2;
                float gx = (float)x + (float)rec[oc >> 3][oc & 7] + fx;
                float gy = (float)y + (float)rec[(oc + 1) >> 3][(oc + 1) & 7] + fy;
                float wgt = a[l * 4 + p] * inv;
                float x0f = floorf(gx), y0f = floorf(gy);
                float wx = gx - x0f, wy = gy - y0f;
                int x0 = (int)x0f, y0 = (int)y0f;
                #pragma unroll
                for (int t_ = 0; t_ < 4; ++t_) {
                    int xi = x0 + (t_ & 1), yi = y0 + (t_ >> 1);
                    float wt = ((t_ & 1) ? wx : 1.f - wx) *
                               ((t_ >> 1) ? wy : 1.f - wy) * wgt;
                    if (xi >= 0 && xi < W && yi >= 0 && yi < H) {
                        const half8 vv = *(const half8*)&img[(long)(yi * W + xi) * 32];
                        #pragma unroll
                        for (int d = 0; d < 8; ++d)
                            o[m * 8 + d] = fmaf(wt, (float)vv[d], o[m * 8 + d]);
                    }
                }
            }
        }
    }
    #pragma unroll
    for (int ch = 0; ch < 32; ++ch)
        out1[((long)b * 32 + ch) * HW + q] = (half_t)o[ch];
}

// ---------------------------------------------------------------------------
// 1x1 conv (32->32) + lrelu, f16 in, fp32 out (final)
// ---------------------------------------------------------------------------
__global__ __launch_bounds__(256) void conv1x1_f16(
    const half_t* __restrict__ in, const float* __restrict__ w,
    const float* __restrict__ bias, float* __restrict__ out, int HW)
{
    int q = blockIdx.x * 256 + threadIdx.x;
    if (q >= HW) return;
    long b = blockIdx.y;
    const half_t* ib = in + b * 32 * HW;
    float v[32];
    #pragma unroll
    for (int ci = 0; ci < 32; ++ci) v[ci] = (float)ib[(long)ci * HW + q];
    float* ob = out + b * 32 * HW;
    #pragma unroll
    for (int co = 0; co < 32; ++co) {
        float acc = bias[co];
        #pragma unroll
        for (int ci = 0; ci < 32; ++ci) acc = fmaf(w[co * 32 + ci], v[ci], acc);
        ob[(long)co * HW + q] = lrelu_f(acc);
    }
}

// ---------------------------------------------------------------------------
extern "C" void kernel_launch(void* const* d_in, const int* in_sizes, int n_in,
                              void* d_out, int out_size, void* d_ws, size_t ws_size,
                              hipStream_t stream)
{
    (void)in_sizes; (void)n_in; (void)out_size; (void)ws_size;
    const int H = 256, W = 256, HW = H * W, B = 2;

    const float* frame    = (const float*)d_in[0];
    const float* srcframe = (const float*)d_in[1];
    const float* ff       = (const float*)d_in[2];
    const float* fb       = (const float*)d_in[3];
    const float* emb_qk_w = (const float*)d_in[4];
    const float* emb_qk_b = (const float*)d_in[5];
    const float* emb_v_w  = (const float*)d_in[6];
    const float* emb_v_b  = (const float*)d_in[7];
    const float* so_w     = (const float*)d_in[8];
    const float* so_b     = (const float*)d_in[9];
    const float* aw_w     = (const float*)d_in[10];
    const float* aw_b     = (const float*)d_in[11];
    const float* vp_w     = (const float*)d_in[12];
    const float* vp_b     = (const float*)d_in[13];
    const float* op_w     = (const float*)d_in[14];
    const float* op_b     = (const float*)d_in[15];
    const float* ff_w     = (const float*)d_in[16];
    const float* ff_b     = (const float*)d_in[17];
    const float* ffn1_w   = (const float*)d_in[18];
    const float* ffn1_b   = (const float*)d_in[19];
    const float* ffn2_w   = (const float*)d_in[20];
    const float* ffn2_b   = (const float*)d_in[21];
    const float* fus_w    = (const float*)d_in[22];
    const float* fus_b    = (const float*)d_in[23];

    half_t* hw = (half_t*)d_ws;
    half_t* q_in16  = hw;                  // 2*100*HW = 13107200
    half_t* query16 = hw + 13107200L;      // 2*96*HW
    half_t* value16 = hw + 25690112L;      // 2*96*HW
    half_t* v_cl    = hw + 38273024L;      // 6*HW*32 channel-last
    half_t* offaw   = hw + 50855936L;      // 2*HW*144 channel-last (off|aw)
    half_t* out1    = hw + 69730304L;      // 2*32*HW
    half_t* out2    = hw + 73924608L;
    half_t* out3    = hw + 78118912L;
    half_t* ffnb    = hw + 82313216L;
    half_t* out4    = hw + 86507520L;
    half_t* wq      = hw + 90701824L;      // 9*4*96*32
    half_t* wv      = hw + 90812416L;      // 9*3*96*32
    half_t* wsoaw   = hw + 90895360L;      // 9*3*144*32
    half_t* wvp     = hw + 91019776L;      // 9*1*32*32
    half_t* wop     = hw + 91028992L;
    half_t* wff     = hw + 91038208L;
    half_t* wffn1   = hw + 91047424L;      // 9*2*32*32
    half_t* wffn2   = hw + 91065856L;

    dim3 blk(256);

    // ---- weight packing ----
    prep_w_cat<100, 96><<<(9 * 4 * 96 * 32 + 255) / 256, blk, 0, stream>>>(emb_qk_w, wq, 0, 96);
    prep_w_cat<96, 96><<<(9 * 3 * 96 * 32 + 255) / 256, blk, 0, stream>>>(emb_v_w, wv, 0, 96);
    prep_w_cat<96, 144><<<(9 * 3 * 96 * 32 + 255) / 256, blk, 0, stream>>>(so_w, wsoaw, 0, 96);
    prep_w_cat<96, 144><<<(9 * 3 * 48 * 32 + 255) / 256, blk, 0, stream>>>(aw_w, wsoaw, 96, 48);
    prep_w_cat<32, 32><<<(9 * 1 * 32 * 32 + 255) / 256, blk, 0, stream>>>(vp_w, wvp, 0, 32);
    prep_w_cat<32, 32><<<(9 * 1 * 32 * 32 + 255) / 256, blk, 0, stream>>>(op_w, wop, 0, 32);
    prep_w_cat<32, 32><<<(9 * 1 * 32 * 32 + 255) / 256, blk, 0, stream>>>(ff_w, wff, 0, 32);
    prep_w_cat<64, 32><<<(9 * 2 * 32 * 32 + 255) / 256, blk, 0, stream>>>(ffn1_w, wffn1, 0, 32);
    prep_w_cat<32, 32><<<(9 * 1 * 32 * 32 + 255) / 256, blk, 0, stream>>>(ffn2_w, wffn2, 0, 32);

    // ---- q_in ----
    build_qin_kernel<<<dim3(HW / 256, B), blk, 0, stream>>>(frame, ff, fb, q_in16, H, W);

    dim3 convGrid(256, B);

    // query = lrelu(conv(q_in, emb_qk))
    conv3x3_mfma<100, 96, 1, true, 0, false, half_t, half_t, 0, 96>
        <<<convGrid, blk, 0, stream>>>(q_in16, 100L * HW, nullptr, 0, wq, emb_qk_b,
                                       nullptr, nullptr, 0, query16, 96L * HW, H, W);
    // value = lrelu(conv(frame, emb_v))
    conv3x3_mfma<96, 96, 1, true, 0, false, float, float, 0, 96>
        <<<convGrid, blk, 0, stream>>>(frame, 96L * HW, nullptr, 0, wv, emb_v_b,
                                       nullptr, nullptr, 0, value16, 96L * HW, H, W);
    // v = conv(value as 6x32ch, vp) -> channel-last [img][pix][32]
    conv3x3_mfma<32, 32, 1, false, 0, false, half_t, half_t, 32, 32>
        <<<dim3(256, 6), blk, 0, stream>>>(value16, 32L * HW, nullptr, 0, wvp, vp_b,
                                           nullptr, nullptr, 0, v_cl, (long)HW * 32, H, W);
    // off|aw = fused conv(query, so_w|aw_w) -> channel-last [pix][144]
    conv3x3_mfma<96, 144, 1, false, 0, false, half_t, half_t, 144, 96>
        <<<convGrid, blk, 0, stream>>>(query16, 96L * HW, nullptr, 0, wsoaw, so_b,
                                       aw_b, nullptr, 0, offaw, (long)HW * 144, H, W);
    // out1 = deformable attention (all heads per thread, 2D tiles)
    deform_v2<<<dim3(256, B), blk, 0, stream>>>(v_cl, offaw, ff, fb, out1, H, W);
    // out2 = conv(out1, op)
    conv3x3_mfma<32, 32, 1, false, 0, false, half_t, half_t, 0, 32>
        <<<convGrid, blk, 0, stream>>>(out1, 32L * HW, nullptr, 0, wop, op_b,
                                       nullptr, nullptr, 0, out2, 32L * HW, H, W);
    // out3 = conv(out2, ff_w) + frame[:,1]
    conv3x3_mfma<32, 32, 1, false, 1, false, half_t, half_t, 0, 32>
        <<<convGrid, blk, 0, stream>>>(out2, 32L * HW, nullptr, 0, wff, ff_b,
                                       nullptr, frame + 32L * HW, 96L * HW, out3, 32L * HW, H, W);
    // ffn = lrelu(conv_dil2(concat(out3, srcframe[:,1]), ffn1))
    conv3x3_mfma<64, 32, 2, true, 0, true, half_t, float, 0, 32>
        <<<convGrid, blk, 0, stream>>>(out3, 32L * HW, srcframe + 32L * HW, 96L * HW,
                                       wffn1, ffn1_b, nullptr, nullptr, 0, ffnb, 32L * HW, H, W);
    // out4 = out3 + conv(ffn, ffn2)
    conv3x3_mfma<32, 32, 1, false, 2, false, half_t, half_t, 0, 32>
        <<<convGrid, blk, 0, stream>>>(ffnb, 32L * HW, nullptr, 0, wffn2, ffn2_b,
                                       nullptr, out3, 32L * HW, out4, 32L * HW, H, W);
    // d_out = lrelu(conv1x1(out4, fus))
    conv1x1_f16<<<dim3(HW / 256, B), blk, 0, stream>>>(out4, fus_w, fus_b,
                                                       (float*)d_out, HW);
}